// Round 1
// baseline (1745.785 us; speedup 1.0000x reference)
//
#include <hip/hip_runtime.h>

// Problem constants (match reference)
#define B_SZ   256
#define D_SZ   128
#define N_ROWS 1000000
#define K1_SZ  2048          // K+1, power of 2
static constexpr float INV_T = 1.0f / 0.07f;

// ---------------------------------------------------------------------------
// Scoring: one 64-lane wave per (b,k) pair. Lane i loads float2 at elem 2i of
// the gathered row -> one coalesced 512B read per row per bank. Butterfly
// shfl reduce, lane 0 writes both outputs.
// out_l[b,k]  = dot(memory_ab[idx[b,k]], l[b])  / T
// out_ab[b,k] = dot(memory_l [idx[b,k]], ab[b]) / T
// ---------------------------------------------------------------------------
__global__ __launch_bounds__(256) void score_kernel(
    const float* __restrict__ l, const float* __restrict__ ab,
    const int* __restrict__ idx,
    const float* __restrict__ memL, const float* __restrict__ memAB,
    float* __restrict__ out_l, float* __restrict__ out_ab)
{
    const int wid  = blockIdx.x * 4 + (threadIdx.x >> 6);   // == b*K1 + k
    const int lane = threadIdx.x & 63;
    const int b    = wid >> 11;                             // / K1_SZ
    const int row  = idx[wid];                              // wave-uniform

    const float2* rowL  = (const float2*)(memL  + (size_t)row * D_SZ);
    const float2* rowAB = (const float2*)(memAB + (size_t)row * D_SZ);
    const float2* lv    = (const float2*)(l  + b * D_SZ);
    const float2* abv   = (const float2*)(ab + b * D_SZ);

    const float2 wl = rowL[lane];
    const float2 wa = rowAB[lane];
    const float2 xa = abv[lane];
    const float2 xl = lv[lane];

    float s_ab = wl.x * xa.x + wl.y * xa.y;   // weight_l . ab
    float s_l  = wa.x * xl.x + wa.y * xl.y;   // weight_ab . l

#pragma unroll
    for (int off = 32; off > 0; off >>= 1) {
        s_ab += __shfl_xor(s_ab, off, 64);
        s_l  += __shfl_xor(s_l,  off, 64);
    }

    if (lane == 0) {
        out_l[wid]  = s_l  * INV_T;
        out_ab[wid] = s_ab * INV_T;
    }
}

// ---------------------------------------------------------------------------
// EMA + L2-normalize + scatter. One wave per sample b, handles both banks.
// Reads OLD memory from d_in (pristine), writes into the copied output banks.
// Duplicate y: last occurrence wins (numpy fancy-assignment semantics).
// ---------------------------------------------------------------------------
__global__ __launch_bounds__(64) void ema_kernel(
    const float* __restrict__ l, const float* __restrict__ ab,
    const int* __restrict__ y,
    const float* __restrict__ memL, const float* __restrict__ memAB,
    float* __restrict__ outML, float* __restrict__ outMAB)
{
    const int b    = blockIdx.x;
    const int lane = threadIdx.x;
    const int yb   = y[b];

    // If any later sample has the same target row, skip (last-write-wins).
    bool dup = false;
    for (int j = b + 1 + lane; j < B_SZ; j += 64)
        if (y[j] == yb) dup = true;
    if (__ballot(dup)) return;

    const float2* mL = (const float2*)(memL  + (size_t)yb * D_SZ);
    const float2* mA = (const float2*)(memAB + (size_t)yb * D_SZ);
    const float2* lv = (const float2*)(l  + b * D_SZ);
    const float2* av = (const float2*)(ab + b * D_SZ);

    const float2 m0 = mL[lane], x0 = lv[lane];
    const float2 m1 = mA[lane], x1 = av[lane];

    float2 vL = { 0.5f * (m0.x + x0.x), 0.5f * (m0.y + x0.y) };
    float2 vA = { 0.5f * (m1.x + x1.x), 0.5f * (m1.y + x1.y) };

    float sL = vL.x * vL.x + vL.y * vL.y;
    float sA = vA.x * vA.x + vA.y * vA.y;
#pragma unroll
    for (int off = 32; off > 0; off >>= 1) {
        sL += __shfl_xor(sL, off, 64);
        sA += __shfl_xor(sA, off, 64);
    }
    const float rL = 1.0f / sqrtf(sL);
    const float rA = 1.0f / sqrtf(sA);

    float2* oL = (float2*)(outML  + (size_t)yb * D_SZ);
    float2* oA = (float2*)(outMAB + (size_t)yb * D_SZ);
    oL[lane] = make_float2(vL.x * rL, vL.y * rL);
    oA[lane] = make_float2(vA.x * rA, vA.y * rA);
}

extern "C" void kernel_launch(void* const* d_in, const int* in_sizes, int n_in,
                              void* d_out, int out_size, void* d_ws, size_t ws_size,
                              hipStream_t stream)
{
    const float* l     = (const float*)d_in[0];
    const float* ab    = (const float*)d_in[1];
    const int*   y     = (const int*)  d_in[2];
    const int*   idx   = (const int*)  d_in[3];
    const float* memL  = (const float*)d_in[4];
    const float* memAB = (const float*)d_in[5];

    float* out    = (float*)d_out;
    float* out_l  = out;                                   // [B, K1, 1]
    float* out_ab = out + (size_t)B_SZ * K1_SZ;            // [B, K1, 1]
    float* outML  = out + (size_t)2 * B_SZ * K1_SZ;        // [N, D]
    float* outMAB = outML + (size_t)N_ROWS * D_SZ;         // [N, D]

    // 1) scoring from pristine memory banks (gathered reads)
    score_kernel<<<(B_SZ * K1_SZ) / 4, 256, 0, stream>>>(
        l, ab, idx, memL, memAB, out_l, out_ab);

    // 2) pass-through copy of both memory banks (1 GB total write)
    hipMemcpyAsync(outML,  memL,  (size_t)N_ROWS * D_SZ * sizeof(float),
                   hipMemcpyDeviceToDevice, stream);
    hipMemcpyAsync(outMAB, memAB, (size_t)N_ROWS * D_SZ * sizeof(float),
                   hipMemcpyDeviceToDevice, stream);

    // 3) EMA + normalize + scatter into the copied banks
    ema_kernel<<<B_SZ, 64, 0, stream>>>(l, ab, y, memL, memAB, outML, outMAB);
}